// Round 1
// baseline (977.506 us; speedup 1.0000x reference)
//
#include <hip/hip_runtime.h>
#include <hip/hip_bf16.h>
#include <math.h>

typedef __attribute__((ext_vector_type(8))) __bf16 bf16x8;
typedef __attribute__((ext_vector_type(4))) float f32x4;
typedef unsigned int uint32;

static constexpr int kC   = 384;
static constexpr int kNH  = 12;
static constexpr int kDH  = 32;
static constexpr int kT   = 64;      // tokens per window
static constexpr int kB   = 16;
static constexpr int kH   = 64;
static constexpr int kW   = 64;
static constexpr int kDFF = 1536;
static constexpr long kNTOK = 65536;             // B*H*W
static constexpr long kNT  = kNTOK * kC;         // elements of one (tokens x C) activation

__device__ __forceinline__ float bf_lo(uint32 u){ return __uint_as_float(u << 16); }
__device__ __forceinline__ float bf_hi(uint32 u){ return __uint_as_float(u & 0xffff0000u); }

// ---------------- weight transpose (K x N fp32 -> N x K bf16) ----------------
__global__ void k_transpose_cast(const float* __restrict__ src, __bf16* __restrict__ dst,
                                 int K, int N)
{
    int o = blockIdx.x * 256 + threadIdx.x;
    if (o >= K * N) return;
    int n = o / K, k = o - n * K;
    dst[o] = (__bf16)src[(size_t)k * N + n];
}

// ---------------- shift2d + window partition + bf16 cast ----------------
// Output Aw[m][c], m = window-token order: m = wi*64 + t, wi = b*64 + (h/8)*8 + (w/8),
// t = (h%8)*8 + (w%8).
__global__ __launch_bounds__(256) void k_shift_window(const float* __restrict__ x,
                                                      __bf16* __restrict__ Aw)
{
    int tid = blockIdx.x * 256 + threadIdx.x;   // 0 .. 65536*48
    int m = tid / 48;
    int g = tid - m * 48;
    int c0 = g * 8;
    int wi = m >> 6, t = m & 63;
    int b = wi >> 6, nh = (wi >> 3) & 7, nw = wi & 7;
    int h = nh * 8 + (t >> 3);
    int w = nw * 8 + (t & 7);
    int q = c0 / 96;
    int sh = h, sw = w;
    bool ok;
    if      (q == 0) { sh = h - 1; ok = (h >= 1);  }
    else if (q == 1) { sh = h + 1; ok = (h <= 62); }
    else if (q == 2) { sw = w - 1; ok = (w >= 1);  }
    else             { sw = w + 1; ok = (w <= 62); }

    __bf16 r[8] __attribute__((aligned(16)));
    if (ok) {
        const float4* src = reinterpret_cast<const float4*>(
            x + (((size_t)b * kH + sh) * kW + sw) * kC + c0);
        float4 v0 = src[0], v1 = src[1];
        r[0] = (__bf16)v0.x; r[1] = (__bf16)v0.y; r[2] = (__bf16)v0.z; r[3] = (__bf16)v0.w;
        r[4] = (__bf16)v1.x; r[5] = (__bf16)v1.y; r[6] = (__bf16)v1.z; r[7] = (__bf16)v1.w;
    } else {
        #pragma unroll
        for (int i = 0; i < 8; ++i) r[i] = (__bf16)0.0f;
    }
    *reinterpret_cast<int4*>(Aw + (size_t)m * kC + c0) = *reinterpret_cast<int4*>(r);
}

// ---------------- generic bf16 MFMA GEMM: C = A(MxK) * B^T(NxK) ----------------
// A row-major (K contiguous), B pre-transposed row-major N x K (K contiguous).
// EPI 0: qkv scatter to q/k/v buffers [win][head][t][dh] bf16 (Cout = qkv base)
// EPI 1: plain bf16 store row-major M x N
// EPI 2: exact gelu then bf16 store
template<int EPI>
__global__ __launch_bounds__(256) void k_gemm(const __bf16* __restrict__ A,
                                              const __bf16* __restrict__ B,
                                              __bf16* __restrict__ Cout,
                                              int N, int K)
{
    __shared__ __bf16 As[128 * 32];
    __shared__ __bf16 Bs[128 * 32];
    const int tid  = threadIdx.x;
    const int wave = tid >> 6, lane = tid & 63;
    const int m0 = blockIdx.x * 128, n0 = blockIdx.y * 128;
    const int wr = (wave >> 1) * 64, wc = (wave & 1) * 64;

    f32x4 acc[4][4] = {};

    for (int k0 = 0; k0 < K; k0 += 32) {
        #pragma unroll
        for (int i = 0; i < 2; ++i) {
            int idx = tid + i * 256;          // 0..511
            int row = idx >> 2, seg = idx & 3;
            __builtin_amdgcn_global_load_lds(
                (const __attribute__((address_space(1))) void*)(A + (size_t)(m0 + row) * K + k0 + seg * 8),
                (__attribute__((address_space(3))) void*)(&As[idx * 8]), 16, 0, 0);
            __builtin_amdgcn_global_load_lds(
                (const __attribute__((address_space(1))) void*)(B + (size_t)(n0 + row) * K + k0 + seg * 8),
                (__attribute__((address_space(3))) void*)(&Bs[idx * 8]), 16, 0, 0);
        }
        asm volatile("s_waitcnt vmcnt(0)" ::: "memory");
        __syncthreads();

        bf16x8 af[4], bfr[4];
        #pragma unroll
        for (int mi = 0; mi < 4; ++mi)
            af[mi] = *reinterpret_cast<const bf16x8*>(&As[(wr + mi * 16 + (lane & 15)) * 32 + (lane >> 4) * 8]);
        #pragma unroll
        for (int ni = 0; ni < 4; ++ni)
            bfr[ni] = *reinterpret_cast<const bf16x8*>(&Bs[(wc + ni * 16 + (lane & 15)) * 32 + (lane >> 4) * 8]);
        #pragma unroll
        for (int mi = 0; mi < 4; ++mi)
            #pragma unroll
            for (int ni = 0; ni < 4; ++ni)
                acc[mi][ni] = __builtin_amdgcn_mfma_f32_16x16x32_bf16(af[mi], bfr[ni], acc[mi][ni], 0, 0, 0);
        __syncthreads();
    }

    #pragma unroll
    for (int mi = 0; mi < 4; ++mi) {
        #pragma unroll
        for (int ni = 0; ni < 4; ++ni) {
            #pragma unroll
            for (int r = 0; r < 4; ++r) {
                int row = m0 + wr + mi * 16 + ((lane >> 4) << 2) + r;
                int col = n0 + wc + ni * 16 + (lane & 15);
                float v = acc[mi][ni][r];
                if constexpr (EPI == 0) {
                    int s   = col / 384;
                    int rem = col - s * 384;
                    int hh  = rem >> 5, d = rem & 31;
                    Cout[(size_t)s * kNT + ((((size_t)(row >> 6)) * kNH + hh) * 64 + (row & 63)) * kDH + d] = (__bf16)v;
                } else if constexpr (EPI == 1) {
                    Cout[(size_t)row * N + col] = (__bf16)v;
                } else {
                    float gl = 0.5f * v * (1.0f + erff(v * 0.70710678118654752f));
                    Cout[(size_t)row * N + col] = (__bf16)gl;
                }
            }
        }
    }
}

// ---------------- per (window, head) attention ----------------
// qkv: q at [0], k at [kNT], v at [2*kNT]; each laid out [win][head][t][dh] bf16.
// One wave per (window, head); lane = query row t. Output AO[m][head*32+d] bf16 (window order).
__global__ __launch_bounds__(256) void k_attn(const __bf16* __restrict__ qkv,
                                              __bf16* __restrict__ AO)
{
    __shared__ __bf16 Ks[4][kT * kDH];
    __shared__ __bf16 Vs[4][kT * kDH];
    const int wave = threadIdx.x >> 6, lane = threadIdx.x & 63;
    const int pair = blockIdx.x * 4 + wave;          // 0..12287
    const int wi = pair / kNH, hh = pair - wi * kNH;

    const __bf16* Qp = qkv + (((size_t)wi * kNH + hh) * kT) * kDH;
    const __bf16* Kp = Qp + kNT;
    const __bf16* Vp = Qp + 2 * kNT;

    {
        const int4* ksrc = reinterpret_cast<const int4*>(Kp + (size_t)lane * kDH);
        const int4* vsrc = reinterpret_cast<const int4*>(Vp + (size_t)lane * kDH);
        int4* kdst = reinterpret_cast<int4*>(&Ks[wave][lane * kDH]);
        int4* vdst = reinterpret_cast<int4*>(&Vs[wave][lane * kDH]);
        #pragma unroll
        for (int i = 0; i < 4; ++i) { kdst[i] = ksrc[i]; vdst[i] = vsrc[i]; }
    }
    __syncthreads();

    // q row (lane = t)
    float q[32];
    {
        const int4* qs = reinterpret_cast<const int4*>(Qp + (size_t)lane * kDH);
        #pragma unroll
        for (int i = 0; i < 4; ++i) {
            int4 v = qs[i];
            uint32 u0 = (uint32)v.x, u1 = (uint32)v.y, u2 = (uint32)v.z, u3 = (uint32)v.w;
            q[i * 8 + 0] = bf_lo(u0); q[i * 8 + 1] = bf_hi(u0);
            q[i * 8 + 2] = bf_lo(u1); q[i * 8 + 3] = bf_hi(u1);
            q[i * 8 + 4] = bf_lo(u2); q[i * 8 + 5] = bf_hi(u2);
            q[i * 8 + 6] = bf_lo(u3); q[i * 8 + 7] = bf_hi(u3);
        }
    }

    const float scale = 0.17677669529663687f;  // 32^-0.5
    float s[64];
    #pragma unroll
    for (int j = 0; j < 64; ++j) {
        const uint32* krow = reinterpret_cast<const uint32*>(&Ks[wave][j * kDH]);
        float a = 0.f;
        #pragma unroll
        for (int d2 = 0; d2 < 16; ++d2) {
            uint32 u = krow[d2];
            a += q[2 * d2] * bf_lo(u) + q[2 * d2 + 1] * bf_hi(u);
        }
        s[j] = a * scale;
    }

    float mx = -INFINITY;
    #pragma unroll
    for (int j = 0; j < 64; ++j) mx = fmaxf(mx, s[j]);
    float sum = 0.f;
    #pragma unroll
    for (int j = 0; j < 64; ++j) { s[j] = __expf(s[j] - mx); sum += s[j]; }
    float inv = 1.0f / sum;

    float o[32] = {};
    #pragma unroll
    for (int j = 0; j < 64; ++j) {
        float p = s[j];
        const uint32* vrow = reinterpret_cast<const uint32*>(&Vs[wave][j * kDH]);
        #pragma unroll
        for (int d2 = 0; d2 < 16; ++d2) {
            uint32 u = vrow[d2];
            o[2 * d2]     += p * bf_lo(u);
            o[2 * d2 + 1] += p * bf_hi(u);
        }
    }

    __bf16* dst = AO + ((size_t)wi * 64 + lane) * kC + hh * kDH;
    __bf16 r[32] __attribute__((aligned(16)));
    #pragma unroll
    for (int d = 0; d < 32; ++d) r[d] = (__bf16)(o[d] * inv);
    #pragma unroll
    for (int i = 0; i < 4; ++i)
        reinterpret_cast<int4*>(dst)[i] = reinterpret_cast<int4*>(r)[i];
}

// ---------------- LN(no-bias) + residual, window-order input ----------------
// x1 = x + LN(P) * gamma ; P is window-token order, x natural order; writes X1 bf16 (natural).
__global__ __launch_bounds__(256) void k_ln_res1(const __bf16* __restrict__ P,
                                                 const float* __restrict__ x,
                                                 const float* __restrict__ gamma,
                                                 __bf16* __restrict__ X1)
{
    const int wave = threadIdx.x >> 6, lane = threadIdx.x & 63;
    const int tok = blockIdx.x * 4 + wave;     // natural: b*4096 + h*64 + w
    const int b = tok >> 12, hw = tok & 4095, h = hw >> 6, w = hw & 63;
    const int m = (((b << 6) | ((h >> 3) << 3) | (w >> 3)) << 6) | (((h & 7) << 3) | (w & 7));

    float p[6]; float sum = 0.f, sq = 0.f;
    #pragma unroll
    for (int i = 0; i < 6; ++i) {
        p[i] = (float)P[(size_t)m * kC + lane + i * 64];
        sum += p[i]; sq += p[i] * p[i];
    }
    #pragma unroll
    for (int off = 32; off; off >>= 1) { sum += __shfl_xor(sum, off); sq += __shfl_xor(sq, off); }
    float mean = sum * (1.0f / kC);
    float var  = sq * (1.0f / kC) - mean * mean;
    float rs   = rsqrtf(var + 1e-5f);
    #pragma unroll
    for (int i = 0; i < 6; ++i) {
        int c = lane + i * 64;
        float v = x[(size_t)tok * kC + c] + (p[i] - mean) * rs * gamma[c];
        X1[(size_t)tok * kC + c] = (__bf16)v;
    }
}

// ---------------- LN(no-bias) + residual, natural order, fp32 out ----------------
__global__ __launch_bounds__(256) void k_ln_res2(const __bf16* __restrict__ F,
                                                 const __bf16* __restrict__ X1,
                                                 const float* __restrict__ gamma,
                                                 float* __restrict__ out)
{
    const int wave = threadIdx.x >> 6, lane = threadIdx.x & 63;
    const size_t tok = blockIdx.x * 4 + wave;

    float f[6]; float sum = 0.f, sq = 0.f;
    #pragma unroll
    for (int i = 0; i < 6; ++i) {
        f[i] = (float)F[tok * kC + lane + i * 64];
        sum += f[i]; sq += f[i] * f[i];
    }
    #pragma unroll
    for (int off = 32; off; off >>= 1) { sum += __shfl_xor(sum, off); sq += __shfl_xor(sq, off); }
    float mean = sum * (1.0f / kC);
    float var  = sq * (1.0f / kC) - mean * mean;
    float rs   = rsqrtf(var + 1e-5f);
    #pragma unroll
    for (int i = 0; i < 6; ++i) {
        int c = lane + i * 64;
        out[tok * kC + c] = (float)X1[tok * kC + c] + (f[i] - mean) * rs * gamma[c];
    }
}

extern "C" void kernel_launch(void* const* d_in, const int* in_sizes, int n_in,
                              void* d_out, int out_size, void* d_ws, size_t ws_size,
                              hipStream_t stream) {
    const float* x    = (const float*)d_in[0];
    const float* wqkv = (const float*)d_in[1];
    const float* wout = (const float*)d_in[2];
    const float* g_at = (const float*)d_in[3];
    const float* w1   = (const float*)d_in[4];
    const float* w2   = (const float*)d_in[5];
    const float* g_ff = (const float*)d_in[6];
    float* out = (float*)d_out;

    char* ws = (char*)d_ws;
    size_t off = 0;
    auto alloc = [&](size_t bytes) { size_t o = off; off += (bytes + 255) & ~(size_t)255; return o; };
    __bf16* WqkvT = (__bf16*)(ws + alloc((size_t)1152 * 384 * 2));
    __bf16* WoutT = (__bf16*)(ws + alloc((size_t)384 * 384 * 2));
    __bf16* W1T   = (__bf16*)(ws + alloc((size_t)1536 * 384 * 2));
    __bf16* W2T   = (__bf16*)(ws + alloc((size_t)384 * 1536 * 2));
    __bf16* R1    = (__bf16*)(ws + alloc((size_t)kNTOK * kDFF * 2));  // qkv (3*kNT) / FFN hidden
    __bf16* R2    = (__bf16*)(ws + alloc((size_t)kNT * 2));           // Aw -> AO -> X1
    __bf16* R3    = (__bf16*)(ws + alloc((size_t)kNT * 2));           // P -> F

    // weights -> bf16, transposed to N x K
    k_transpose_cast<<<dim3((384 * 1152 + 255) / 256), 256, 0, stream>>>(wqkv, WqkvT, 384, 1152);
    k_transpose_cast<<<dim3((384 * 384 + 255) / 256), 256, 0, stream>>>(wout, WoutT, 384, 384);
    k_transpose_cast<<<dim3((384 * 1536 + 255) / 256), 256, 0, stream>>>(w1, W1T, 384, 1536);
    k_transpose_cast<<<dim3((1536 * 384 + 255) / 256), 256, 0, stream>>>(w2, W2T, 1536, 384);

    // shift2d + window partition
    k_shift_window<<<dim3(12288), 256, 0, stream>>>(x, R2);

    // qkv projection (scatter epilogue into q/k/v)
    k_gemm<0><<<dim3(512, 9), 256, 0, stream>>>(R2, WqkvT, R1, 1152, 384);

    // window attention
    k_attn<<<dim3(3072), 256, 0, stream>>>(R1, R2);

    // output projection
    k_gemm<1><<<dim3(512, 3), 256, 0, stream>>>(R2, WoutT, R3, 384, 384);

    // x1 = x + LN(attn)
    k_ln_res1<<<dim3(16384), 256, 0, stream>>>(R3, x, g_at, R2);

    // FFN up + gelu
    k_gemm<2><<<dim3(512, 12), 256, 0, stream>>>(R2, W1T, R1, 1536, 384);

    // FFN down
    k_gemm<1><<<dim3(512, 3), 256, 0, stream>>>(R1, W2T, R3, 384, 1536);

    // out = x1 + LN(f)
    k_ln_res2<<<dim3(16384), 256, 0, stream>>>(R3, R2, g_ff, out);
}

// Round 2
// 610.233 us; speedup vs baseline: 1.6019x; 1.6019x over previous
//
#include <hip/hip_runtime.h>
#include <hip/hip_bf16.h>
#include <math.h>

typedef __attribute__((ext_vector_type(8))) __bf16 bf16x8;
typedef __attribute__((ext_vector_type(4))) float f32x4;
typedef unsigned int uint32;

static constexpr int kC   = 384;
static constexpr int kNH  = 12;
static constexpr int kDH  = 32;
static constexpr int kT   = 64;      // tokens per window
static constexpr int kB   = 16;
static constexpr int kH   = 64;
static constexpr int kW   = 64;
static constexpr int kDFF = 1536;
static constexpr long kNTOK = 65536;             // B*H*W
static constexpr long kNT  = kNTOK * kC;         // elements of one (tokens x C) activation

__device__ __forceinline__ float bf_lo(uint32 u){ return __uint_as_float(u << 16); }
__device__ __forceinline__ float bf_hi(uint32 u){ return __uint_as_float(u & 0xffff0000u); }

// ---------------- weight transpose (K x N fp32 -> N x K bf16) ----------------
__global__ void k_transpose_cast(const float* __restrict__ src, __bf16* __restrict__ dst,
                                 int K, int N)
{
    int o = blockIdx.x * 256 + threadIdx.x;
    if (o >= K * N) return;
    int n = o / K, k = o - n * K;
    dst[o] = (__bf16)src[(size_t)k * N + n];
}

// ---------------- shift2d + window partition + bf16 cast ----------------
__global__ __launch_bounds__(256) void k_shift_window(const float* __restrict__ x,
                                                      __bf16* __restrict__ Aw)
{
    int tid = blockIdx.x * 256 + threadIdx.x;   // 0 .. 65536*48
    int m = tid / 48;
    int g = tid - m * 48;
    int c0 = g * 8;
    int wi = m >> 6, t = m & 63;
    int b = wi >> 6, nh = (wi >> 3) & 7, nw = wi & 7;
    int h = nh * 8 + (t >> 3);
    int w = nw * 8 + (t & 7);
    int q = c0 / 96;
    int sh = h, sw = w;
    bool ok;
    if      (q == 0) { sh = h - 1; ok = (h >= 1);  }
    else if (q == 1) { sh = h + 1; ok = (h <= 62); }
    else if (q == 2) { sw = w - 1; ok = (w >= 1);  }
    else             { sw = w + 1; ok = (w <= 62); }

    __bf16 r[8] __attribute__((aligned(16)));
    if (ok) {
        const float4* src = reinterpret_cast<const float4*>(
            x + (((size_t)b * kH + sh) * kW + sw) * kC + c0);
        float4 v0 = src[0], v1 = src[1];
        r[0] = (__bf16)v0.x; r[1] = (__bf16)v0.y; r[2] = (__bf16)v0.z; r[3] = (__bf16)v0.w;
        r[4] = (__bf16)v1.x; r[5] = (__bf16)v1.y; r[6] = (__bf16)v1.z; r[7] = (__bf16)v1.w;
    } else {
        #pragma unroll
        for (int i = 0; i < 8; ++i) r[i] = (__bf16)0.0f;
    }
    *reinterpret_cast<int4*>(Aw + (size_t)m * kC + c0) = *reinterpret_cast<int4*>(r);
}

// ---------------- generic bf16 MFMA GEMM: C = A(MxK) * B^T(NxK) ----------------
template<int EPI>
__global__ __launch_bounds__(256) void k_gemm(const __bf16* __restrict__ A,
                                              const __bf16* __restrict__ B,
                                              __bf16* __restrict__ Cout,
                                              int N, int K)
{
    __shared__ __bf16 As[128 * 32];
    __shared__ __bf16 Bs[128 * 32];
    const int tid  = threadIdx.x;
    const int wave = tid >> 6, lane = tid & 63;
    const int m0 = blockIdx.x * 128, n0 = blockIdx.y * 128;
    const int wr = (wave >> 1) * 64, wc = (wave & 1) * 64;

    f32x4 acc[4][4] = {};

    for (int k0 = 0; k0 < K; k0 += 32) {
        #pragma unroll
        for (int i = 0; i < 2; ++i) {
            int idx = tid + i * 256;          // 0..511
            int row = idx >> 2, seg = idx & 3;
            __builtin_amdgcn_global_load_lds(
                (const __attribute__((address_space(1))) void*)(A + (size_t)(m0 + row) * K + k0 + seg * 8),
                (__attribute__((address_space(3))) void*)(&As[idx * 8]), 16, 0, 0);
            __builtin_amdgcn_global_load_lds(
                (const __attribute__((address_space(1))) void*)(B + (size_t)(n0 + row) * K + k0 + seg * 8),
                (__attribute__((address_space(3))) void*)(&Bs[idx * 8]), 16, 0, 0);
        }
        asm volatile("s_waitcnt vmcnt(0)" ::: "memory");
        __syncthreads();

        bf16x8 af[4], bfr[4];
        #pragma unroll
        for (int mi = 0; mi < 4; ++mi)
            af[mi] = *reinterpret_cast<const bf16x8*>(&As[(wr + mi * 16 + (lane & 15)) * 32 + (lane >> 4) * 8]);
        #pragma unroll
        for (int ni = 0; ni < 4; ++ni)
            bfr[ni] = *reinterpret_cast<const bf16x8*>(&Bs[(wc + ni * 16 + (lane & 15)) * 32 + (lane >> 4) * 8]);
        #pragma unroll
        for (int mi = 0; mi < 4; ++mi)
            #pragma unroll
            for (int ni = 0; ni < 4; ++ni)
                acc[mi][ni] = __builtin_amdgcn_mfma_f32_16x16x32_bf16(af[mi], bfr[ni], acc[mi][ni], 0, 0, 0);
        __syncthreads();
    }

    #pragma unroll
    for (int mi = 0; mi < 4; ++mi) {
        #pragma unroll
        for (int ni = 0; ni < 4; ++ni) {
            #pragma unroll
            for (int r = 0; r < 4; ++r) {
                int row = m0 + wr + mi * 16 + ((lane >> 4) << 2) + r;
                int col = n0 + wc + ni * 16 + (lane & 15);
                float v = acc[mi][ni][r];
                if constexpr (EPI == 0) {
                    int s   = col / 384;
                    int rem = col - s * 384;
                    int hh  = rem >> 5, d = rem & 31;
                    Cout[(size_t)s * kNT + ((((size_t)(row >> 6)) * kNH + hh) * 64 + (row & 63)) * kDH + d] = (__bf16)v;
                } else if constexpr (EPI == 1) {
                    Cout[(size_t)row * N + col] = (__bf16)v;
                } else {
                    float gl = 0.5f * v * (1.0f + erff(v * 0.70710678118654752f));
                    Cout[(size_t)row * N + col] = (__bf16)gl;
                }
            }
        }
    }
}

// ---------------- MFMA window attention: one wave per (window, head) ----------------
// qkv: q at [0], k at [kNT], v at [2*kNT]; each laid out [win][head][t][dh] bf16.
// Output AO[m][head*32+d] bf16 (window-token order).
__global__ __launch_bounds__(256) void k_attn(const __bf16* __restrict__ qkv,
                                              __bf16* __restrict__ AO)
{
    __shared__ __bf16 Pl[4][kT * kT];   // 8 KB per wave, XOR-swizzled P tile
    const int wave = threadIdx.x >> 6, lane = threadIdx.x & 63;
    const int pair = blockIdx.x * 4 + wave;          // 0..12287
    const int wi = pair / kNH, hh = pair - wi * kNH;
    const int g = lane >> 4, qh = lane & 15;

    const __bf16* Qp = qkv + ((size_t)wi * kNH + hh) * (kT * kDH);
    const __bf16* Kp = Qp + kNT;
    const __bf16* Vp = Qp + 2 * kNT;
    char* Pb = (char*)&Pl[wave][0];

    // ---- QK^T: S[m][n] = sum_k Q[m][k] K[n][k], 16 tiles of 16x16 (K=32, 1 MFMA each)
    bf16x8 qa[4], kb[4];
    #pragma unroll
    for (int mi = 0; mi < 4; ++mi)
        qa[mi] = *reinterpret_cast<const bf16x8*>(Qp + (mi * 16 + qh) * kDH + g * 8);
    #pragma unroll
    for (int ni = 0; ni < 4; ++ni)
        kb[ni] = *reinterpret_cast<const bf16x8*>(Kp + (ni * 16 + qh) * kDH + g * 8);

    f32x4 s[4][4] = {};
    #pragma unroll
    for (int mi = 0; mi < 4; ++mi)
        #pragma unroll
        for (int ni = 0; ni < 4; ++ni)
            s[mi][ni] = __builtin_amdgcn_mfma_f32_16x16x32_bf16(qa[mi], kb[ni], s[mi][ni], 0, 0, 0);

    // ---- softmax over keys (cols). Lane holds rows (mi*16 + g*4 + reg), cols (ni*16 + qh).
    const float scale = 0.17677669529663687f;  // 32^-0.5
    float rmax[4][4], rsum[4][4];
    #pragma unroll
    for (int mi = 0; mi < 4; ++mi)
        #pragma unroll
        for (int r = 0; r < 4; ++r) {
            float a = fmaxf(fmaxf(s[mi][0][r], s[mi][1][r]), fmaxf(s[mi][2][r], s[mi][3][r]));
            #pragma unroll
            for (int st = 1; st < 16; st <<= 1) a = fmaxf(a, __shfl_xor(a, st));
            rmax[mi][r] = a;
        }
    #pragma unroll
    for (int mi = 0; mi < 4; ++mi)
        #pragma unroll
        for (int r = 0; r < 4; ++r) {
            float acc = 0.f;
            #pragma unroll
            for (int ni = 0; ni < 4; ++ni) {
                float p = __expf((s[mi][ni][r] - rmax[mi][r]) * scale);
                s[mi][ni][r] = p;
                acc += p;
            }
            #pragma unroll
            for (int st = 1; st < 16; st <<= 1) acc += __shfl_xor(acc, st);
            rsum[mi][r] = 1.0f / acc;
        }

    // ---- write P (bf16) to LDS, XOR-swizzled: byte ^= (row&7)<<4
    #pragma unroll
    for (int mi = 0; mi < 4; ++mi)
        #pragma unroll
        for (int ni = 0; ni < 4; ++ni)
            #pragma unroll
            for (int r = 0; r < 4; ++r) {
                int row = mi * 16 + g * 4 + r;
                int col = ni * 16 + qh;
                uint32 byte = (uint32)((row << 7) | (col << 1)) ^ (uint32)((row & 7) << 4);
                *reinterpret_cast<__bf16*>(Pb + byte) = (__bf16)s[mi][ni][r];
            }

    // ---- PV: O[m][d] = sum_k P[m][k] V[k][d], tiles mi(4) x ni2(2), K=64 (2 MFMA)
    f32x4 o[4][2] = {};
    #pragma unroll
    for (int kk = 0; kk < 2; ++kk) {
        bf16x8 pa[4], vb[2];
        #pragma unroll
        for (int mi = 0; mi < 4; ++mi) {
            int row = mi * 16 + qh;
            uint32 byte = (uint32)((row << 7) | (kk << 6) | (g << 4)) ^ (uint32)((row & 7) << 4);
            pa[mi] = *reinterpret_cast<const bf16x8*>(Pb + byte);
        }
        #pragma unroll
        for (int n2 = 0; n2 < 2; ++n2) {
            __bf16 tmp[8];
            #pragma unroll
            for (int j = 0; j < 8; ++j)
                tmp[j] = Vp[(kk * 32 + g * 8 + j) * kDH + n2 * 16 + qh];
            vb[n2] = *reinterpret_cast<const bf16x8*>(tmp);
        }
        #pragma unroll
        for (int mi = 0; mi < 4; ++mi)
            #pragma unroll
            for (int n2 = 0; n2 < 2; ++n2)
                o[mi][n2] = __builtin_amdgcn_mfma_f32_16x16x32_bf16(pa[mi], vb[n2], o[mi][n2], 0, 0, 0);
    }

    // ---- normalize + store (C/D rows match rsum rows exactly)
    #pragma unroll
    for (int mi = 0; mi < 4; ++mi)
        #pragma unroll
        for (int n2 = 0; n2 < 2; ++n2)
            #pragma unroll
            for (int r = 0; r < 4; ++r) {
                int row = mi * 16 + g * 4 + r;
                AO[((size_t)wi * 64 + row) * kC + hh * kDH + n2 * 16 + qh] =
                    (__bf16)(o[mi][n2][r] * rsum[mi][r]);
            }
}

// ---------------- LN(no-bias) + residual, window-order input ----------------
__global__ __launch_bounds__(256) void k_ln_res1(const __bf16* __restrict__ P,
                                                 const float* __restrict__ x,
                                                 const float* __restrict__ gamma,
                                                 __bf16* __restrict__ X1)
{
    const int wave = threadIdx.x >> 6, lane = threadIdx.x & 63;
    const int tok = blockIdx.x * 4 + wave;     // natural: b*4096 + h*64 + w
    const int b = tok >> 12, hw = tok & 4095, h = hw >> 6, w = hw & 63;
    const int m = (((b << 6) | ((h >> 3) << 3) | (w >> 3)) << 6) | (((h & 7) << 3) | (w & 7));

    float p[6]; float sum = 0.f, sq = 0.f;
    #pragma unroll
    for (int i = 0; i < 6; ++i) {
        p[i] = (float)P[(size_t)m * kC + lane + i * 64];
        sum += p[i]; sq += p[i] * p[i];
    }
    #pragma unroll
    for (int off = 32; off; off >>= 1) { sum += __shfl_xor(sum, off); sq += __shfl_xor(sq, off); }
    float mean = sum * (1.0f / kC);
    float var  = sq * (1.0f / kC) - mean * mean;
    float rs   = rsqrtf(var + 1e-5f);
    #pragma unroll
    for (int i = 0; i < 6; ++i) {
        int c = lane + i * 64;
        float v = x[(size_t)tok * kC + c] + (p[i] - mean) * rs * gamma[c];
        X1[(size_t)tok * kC + c] = (__bf16)v;
    }
}

// ---------------- LN(no-bias) + residual, natural order, fp32 out ----------------
__global__ __launch_bounds__(256) void k_ln_res2(const __bf16* __restrict__ F,
                                                 const __bf16* __restrict__ X1,
                                                 const float* __restrict__ gamma,
                                                 float* __restrict__ out)
{
    const int wave = threadIdx.x >> 6, lane = threadIdx.x & 63;
    const size_t tok = blockIdx.x * 4 + wave;

    float f[6]; float sum = 0.f, sq = 0.f;
    #pragma unroll
    for (int i = 0; i < 6; ++i) {
        f[i] = (float)F[tok * kC + lane + i * 64];
        sum += f[i]; sq += f[i] * f[i];
    }
    #pragma unroll
    for (int off = 32; off; off >>= 1) { sum += __shfl_xor(sum, off); sq += __shfl_xor(sq, off); }
    float mean = sum * (1.0f / kC);
    float var  = sq * (1.0f / kC) - mean * mean;
    float rs   = rsqrtf(var + 1e-5f);
    #pragma unroll
    for (int i = 0; i < 6; ++i) {
        int c = lane + i * 64;
        out[tok * kC + c] = (float)X1[tok * kC + c] + (f[i] - mean) * rs * gamma[c];
    }
}

extern "C" void kernel_launch(void* const* d_in, const int* in_sizes, int n_in,
                              void* d_out, int out_size, void* d_ws, size_t ws_size,
                              hipStream_t stream) {
    const float* x    = (const float*)d_in[0];
    const float* wqkv = (const float*)d_in[1];
    const float* wout = (const float*)d_in[2];
    const float* g_at = (const float*)d_in[3];
    const float* w1   = (const float*)d_in[4];
    const float* w2   = (const float*)d_in[5];
    const float* g_ff = (const float*)d_in[6];
    float* out = (float*)d_out;

    char* ws = (char*)d_ws;
    size_t off = 0;
    auto alloc = [&](size_t bytes) { size_t o = off; off += (bytes + 255) & ~(size_t)255; return o; };
    __bf16* WqkvT = (__bf16*)(ws + alloc((size_t)1152 * 384 * 2));
    __bf16* WoutT = (__bf16*)(ws + alloc((size_t)384 * 384 * 2));
    __bf16* W1T   = (__bf16*)(ws + alloc((size_t)1536 * 384 * 2));
    __bf16* W2T   = (__bf16*)(ws + alloc((size_t)384 * 1536 * 2));
    __bf16* R1    = (__bf16*)(ws + alloc((size_t)kNTOK * kDFF * 2));  // qkv (3*kNT) / FFN hidden
    __bf16* R2    = (__bf16*)(ws + alloc((size_t)kNT * 2));           // Aw -> AO -> X1
    __bf16* R3    = (__bf16*)(ws + alloc((size_t)kNT * 2));           // P -> F

    // weights -> bf16, transposed to N x K
    k_transpose_cast<<<dim3((384 * 1152 + 255) / 256), 256, 0, stream>>>(wqkv, WqkvT, 384, 1152);
    k_transpose_cast<<<dim3((384 * 384 + 255) / 256), 256, 0, stream>>>(wout, WoutT, 384, 384);
    k_transpose_cast<<<dim3((384 * 1536 + 255) / 256), 256, 0, stream>>>(w1, W1T, 384, 1536);
    k_transpose_cast<<<dim3((1536 * 384 + 255) / 256), 256, 0, stream>>>(w2, W2T, 1536, 384);

    // shift2d + window partition
    k_shift_window<<<dim3(12288), 256, 0, stream>>>(x, R2);

    // qkv projection (scatter epilogue into q/k/v)
    k_gemm<0><<<dim3(512, 9), 256, 0, stream>>>(R2, WqkvT, R1, 1152, 384);

    // window attention (MFMA)
    k_attn<<<dim3(3072), 256, 0, stream>>>(R1, R2);

    // output projection
    k_gemm<1><<<dim3(512, 3), 256, 0, stream>>>(R2, WoutT, R3, 384, 384);

    // x1 = x + LN(attn)
    k_ln_res1<<<dim3(16384), 256, 0, stream>>>(R3, x, g_at, R2);

    // FFN up + gelu
    k_gemm<2><<<dim3(512, 12), 256, 0, stream>>>(R2, W1T, R1, 1536, 384);

    // FFN down
    k_gemm<1><<<dim3(512, 3), 256, 0, stream>>>(R1, W2T, R3, 384, 1536);

    // out = x1 + LN(f)
    k_ln_res2<<<dim3(16384), 256, 0, stream>>>(R3, R2, g_ff, out);
}

// Round 3
// 536.574 us; speedup vs baseline: 1.8218x; 1.1373x over previous
//
#include <hip/hip_runtime.h>
#include <hip/hip_bf16.h>
#include <math.h>

typedef __attribute__((ext_vector_type(8))) __bf16 bf16x8;
typedef __attribute__((ext_vector_type(4))) float f32x4;
typedef unsigned int uint32;

static constexpr int kC   = 384;
static constexpr int kNH  = 12;
static constexpr int kDH  = 32;
static constexpr int kT   = 64;      // tokens per window
static constexpr int kB   = 16;
static constexpr int kH   = 64;
static constexpr int kW   = 64;
static constexpr int kDFF = 1536;
static constexpr long kNTOK = 65536;             // B*H*W
static constexpr long kNT  = kNTOK * kC;         // elements of one (tokens x C) activation

__device__ __forceinline__ float bf_lo(uint32 u){ return __uint_as_float(u << 16); }
__device__ __forceinline__ float bf_hi(uint32 u){ return __uint_as_float(u & 0xffff0000u); }

// ---------------- weight transpose (K x N fp32 -> N x K bf16) ----------------
__global__ void k_transpose_cast(const float* __restrict__ src, __bf16* __restrict__ dst,
                                 int K, int N)
{
    int o = blockIdx.x * 256 + threadIdx.x;
    if (o >= K * N) return;
    int n = o / K, k = o - n * K;
    dst[o] = (__bf16)src[(size_t)k * N + n];
}

// ---------------- shift2d + window partition + bf16 cast ----------------
__global__ __launch_bounds__(256) void k_shift_window(const float* __restrict__ x,
                                                      __bf16* __restrict__ Aw)
{
    int tid = blockIdx.x * 256 + threadIdx.x;   // 0 .. 65536*48
    int m = tid / 48;
    int g = tid - m * 48;
    int c0 = g * 8;
    int wi = m >> 6, t = m & 63;
    int b = wi >> 6, nh = (wi >> 3) & 7, nw = wi & 7;
    int h = nh * 8 + (t >> 3);
    int w = nw * 8 + (t & 7);
    int q = c0 / 96;
    int sh = h, sw = w;
    bool ok;
    if      (q == 0) { sh = h - 1; ok = (h >= 1);  }
    else if (q == 1) { sh = h + 1; ok = (h <= 62); }
    else if (q == 2) { sw = w - 1; ok = (w >= 1);  }
    else             { sw = w + 1; ok = (w <= 62); }

    __bf16 r[8] __attribute__((aligned(16)));
    if (ok) {
        const float4* src = reinterpret_cast<const float4*>(
            x + (((size_t)b * kH + sh) * kW + sw) * kC + c0);
        float4 v0 = src[0], v1 = src[1];
        r[0] = (__bf16)v0.x; r[1] = (__bf16)v0.y; r[2] = (__bf16)v0.z; r[3] = (__bf16)v0.w;
        r[4] = (__bf16)v1.x; r[5] = (__bf16)v1.y; r[6] = (__bf16)v1.z; r[7] = (__bf16)v1.w;
    } else {
        #pragma unroll
        for (int i = 0; i < 8; ++i) r[i] = (__bf16)0.0f;
    }
    *reinterpret_cast<int4*>(Aw + (size_t)m * kC + c0) = *reinterpret_cast<int4*>(r);
}

// ---------------- generic bf16 MFMA GEMM: C = A(MxK) * B^T(NxK) ----------------
// Double-buffered LDS, both-sides bank swizzle, XCD-chunked 1-D grid (n-inner).
template<int EPI>
__global__ __launch_bounds__(256) void k_gemm(const __bf16* __restrict__ A,
                                              const __bf16* __restrict__ B,
                                              __bf16* __restrict__ Cout,
                                              int N, int K, int nt)
{
    __shared__ __align__(16) __bf16 As[2][128 * 32];
    __shared__ __align__(16) __bf16 Bs[2][128 * 32];
    const int tid  = threadIdx.x;
    const int wave = tid >> 6, lane = tid & 63;
    const int g = lane >> 4, qh = lane & 15;

    // XCD-aware bijective swizzle (nwg % 8 == 0 for all our launches), n-tile fastest
    const int nwg = gridDim.x;
    const int wg  = (blockIdx.x & 7) * (nwg >> 3) + (blockIdx.x >> 3);
    const int nb  = wg % nt, mb = wg / nt;
    const int m0 = mb * 128, n0 = nb * 128;
    const int wr = (wave >> 1) * 64, wc = (wave & 1) * 64;

    // read-side swizzled slot (bf16 units): slot = g ^ ((row>>1)&3), row&2-bits == lane bits 1..2
    const int sw = ((g ^ ((lane >> 1) & 3)) << 3);

    auto STAGE = [&](int buf, int k0) {
        #pragma unroll
        for (int i = 0; i < 2; ++i) {
            int idx = tid + i * 256;          // 0..511
            int row = idx >> 2;
            int gseg = (idx & 3) ^ ((idx >> 3) & 3);   // pre-swizzled global source
            __builtin_amdgcn_global_load_lds(
                (const __attribute__((address_space(1))) void*)(A + (size_t)(m0 + row) * K + k0 + gseg * 8),
                (__attribute__((address_space(3))) void*)(&As[buf][idx * 8]), 16, 0, 0);
            __builtin_amdgcn_global_load_lds(
                (const __attribute__((address_space(1))) void*)(B + (size_t)(n0 + row) * K + k0 + gseg * 8),
                (__attribute__((address_space(3))) void*)(&Bs[buf][idx * 8]), 16, 0, 0);
        }
    };

    f32x4 acc[4][4] = {};
    const int nkt = K >> 5;

    STAGE(0, 0);
    for (int t = 0; t < nkt; ++t) {
        const int cur = t & 1;
        __syncthreads();                       // implicit vmcnt(0): drains tile-t loads (issued 1 iter ago)
        if (t + 1 < nkt) STAGE(cur ^ 1, (t + 1) << 5);

        bf16x8 af[4], bfr[4];
        #pragma unroll
        for (int mi = 0; mi < 4; ++mi) {
            int ra = wr + mi * 16 + qh;
            af[mi] = *reinterpret_cast<const bf16x8*>(&As[cur][ra * 32 + sw]);
        }
        #pragma unroll
        for (int ni = 0; ni < 4; ++ni) {
            int rb = wc + ni * 16 + qh;
            bfr[ni] = *reinterpret_cast<const bf16x8*>(&Bs[cur][rb * 32 + sw]);
        }
        #pragma unroll
        for (int mi = 0; mi < 4; ++mi)
            #pragma unroll
            for (int ni = 0; ni < 4; ++ni)
                acc[mi][ni] = __builtin_amdgcn_mfma_f32_16x16x32_bf16(af[mi], bfr[ni], acc[mi][ni], 0, 0, 0);
    }

    #pragma unroll
    for (int mi = 0; mi < 4; ++mi) {
        #pragma unroll
        for (int ni = 0; ni < 4; ++ni) {
            #pragma unroll
            for (int r = 0; r < 4; ++r) {
                int row = m0 + wr + mi * 16 + (g << 2) + r;
                int col = n0 + wc + ni * 16 + qh;
                float v = acc[mi][ni][r];
                if constexpr (EPI == 0) {
                    int s   = col / 384;
                    int rem = col - s * 384;
                    int hh  = rem >> 5, d = rem & 31;
                    Cout[(size_t)s * kNT + ((((size_t)(row >> 6)) * kNH + hh) * 64 + (row & 63)) * kDH + d] = (__bf16)v;
                } else if constexpr (EPI == 1) {
                    Cout[(size_t)row * N + col] = (__bf16)v;
                } else {
                    float gl = 0.5f * v * (1.0f + erff(v * 0.70710678118654752f));
                    Cout[(size_t)row * N + col] = (__bf16)gl;
                }
            }
        }
    }
}

// ---------------- MFMA window attention: one wave per (window, head) ----------------
__global__ __launch_bounds__(256) void k_attn(const __bf16* __restrict__ qkv,
                                              __bf16* __restrict__ AO)
{
    __shared__ __bf16 Pl[4][kT * kT];   // 8 KB per wave, XOR-swizzled P tile
    const int wave = threadIdx.x >> 6, lane = threadIdx.x & 63;
    const int pair = blockIdx.x * 4 + wave;          // 0..12287
    const int wi = pair / kNH, hh = pair - wi * kNH;
    const int g = lane >> 4, qh = lane & 15;

    const __bf16* Qp = qkv + ((size_t)wi * kNH + hh) * (kT * kDH);
    const __bf16* Kp = Qp + kNT;
    const __bf16* Vp = Qp + 2 * kNT;
    char* Pb = (char*)&Pl[wave][0];

    bf16x8 qa[4], kb[4];
    #pragma unroll
    for (int mi = 0; mi < 4; ++mi)
        qa[mi] = *reinterpret_cast<const bf16x8*>(Qp + (mi * 16 + qh) * kDH + g * 8);
    #pragma unroll
    for (int ni = 0; ni < 4; ++ni)
        kb[ni] = *reinterpret_cast<const bf16x8*>(Kp + (ni * 16 + qh) * kDH + g * 8);

    f32x4 s[4][4] = {};
    #pragma unroll
    for (int mi = 0; mi < 4; ++mi)
        #pragma unroll
        for (int ni = 0; ni < 4; ++ni)
            s[mi][ni] = __builtin_amdgcn_mfma_f32_16x16x32_bf16(qa[mi], kb[ni], s[mi][ni], 0, 0, 0);

    const float scale = 0.17677669529663687f;  // 32^-0.5
    float rmax[4][4], rsum[4][4];
    #pragma unroll
    for (int mi = 0; mi < 4; ++mi)
        #pragma unroll
        for (int r = 0; r < 4; ++r) {
            float a = fmaxf(fmaxf(s[mi][0][r], s[mi][1][r]), fmaxf(s[mi][2][r], s[mi][3][r]));
            #pragma unroll
            for (int st = 1; st < 16; st <<= 1) a = fmaxf(a, __shfl_xor(a, st));
            rmax[mi][r] = a;
        }
    #pragma unroll
    for (int mi = 0; mi < 4; ++mi)
        #pragma unroll
        for (int r = 0; r < 4; ++r) {
            float acc = 0.f;
            #pragma unroll
            for (int ni = 0; ni < 4; ++ni) {
                float p = __expf((s[mi][ni][r] - rmax[mi][r]) * scale);
                s[mi][ni][r] = p;
                acc += p;
            }
            #pragma unroll
            for (int st = 1; st < 16; st <<= 1) acc += __shfl_xor(acc, st);
            rsum[mi][r] = 1.0f / acc;
        }

    #pragma unroll
    for (int mi = 0; mi < 4; ++mi)
        #pragma unroll
        for (int ni = 0; ni < 4; ++ni)
            #pragma unroll
            for (int r = 0; r < 4; ++r) {
                int row = mi * 16 + g * 4 + r;
                int col = ni * 16 + qh;
                uint32 byte = (uint32)((row << 7) | (col << 1)) ^ (uint32)((row & 7) << 4);
                *reinterpret_cast<__bf16*>(Pb + byte) = (__bf16)s[mi][ni][r];
            }

    f32x4 o[4][2] = {};
    #pragma unroll
    for (int kk = 0; kk < 2; ++kk) {
        bf16x8 pa[4], vb[2];
        #pragma unroll
        for (int mi = 0; mi < 4; ++mi) {
            int row = mi * 16 + qh;
            uint32 byte = (uint32)((row << 7) | (kk << 6) | (g << 4)) ^ (uint32)((row & 7) << 4);
            pa[mi] = *reinterpret_cast<const bf16x8*>(Pb + byte);
        }
        #pragma unroll
        for (int n2 = 0; n2 < 2; ++n2) {
            __bf16 tmp[8];
            #pragma unroll
            for (int j = 0; j < 8; ++j)
                tmp[j] = Vp[(kk * 32 + g * 8 + j) * kDH + n2 * 16 + qh];
            vb[n2] = *reinterpret_cast<const bf16x8*>(tmp);
        }
        #pragma unroll
        for (int mi = 0; mi < 4; ++mi)
            #pragma unroll
            for (int n2 = 0; n2 < 2; ++n2)
                o[mi][n2] = __builtin_amdgcn_mfma_f32_16x16x32_bf16(pa[mi], vb[n2], o[mi][n2], 0, 0, 0);
    }

    #pragma unroll
    for (int mi = 0; mi < 4; ++mi)
        #pragma unroll
        for (int n2 = 0; n2 < 2; ++n2)
            #pragma unroll
            for (int r = 0; r < 4; ++r) {
                int row = mi * 16 + g * 4 + r;
                AO[((size_t)wi * 64 + row) * kC + hh * kDH + n2 * 16 + qh] =
                    (__bf16)(o[mi][n2][r] * rsum[mi][r]);
            }
}

// ---------------- LN(no-bias) + residual, window-order input ----------------
__global__ __launch_bounds__(256) void k_ln_res1(const __bf16* __restrict__ P,
                                                 const float* __restrict__ x,
                                                 const float* __restrict__ gamma,
                                                 __bf16* __restrict__ X1)
{
    const int wave = threadIdx.x >> 6, lane = threadIdx.x & 63;
    const int tok = blockIdx.x * 4 + wave;     // natural: b*4096 + h*64 + w
    const int b = tok >> 12, hw = tok & 4095, h = hw >> 6, w = hw & 63;
    const int m = (((b << 6) | ((h >> 3) << 3) | (w >> 3)) << 6) | (((h & 7) << 3) | (w & 7));

    float p[6]; float sum = 0.f, sq = 0.f;
    #pragma unroll
    for (int i = 0; i < 6; ++i) {
        p[i] = (float)P[(size_t)m * kC + lane + i * 64];
        sum += p[i]; sq += p[i] * p[i];
    }
    #pragma unroll
    for (int off = 32; off; off >>= 1) { sum += __shfl_xor(sum, off); sq += __shfl_xor(sq, off); }
    float mean = sum * (1.0f / kC);
    float var  = sq * (1.0f / kC) - mean * mean;
    float rs   = rsqrtf(var + 1e-5f);
    #pragma unroll
    for (int i = 0; i < 6; ++i) {
        int c = lane + i * 64;
        float v = x[(size_t)tok * kC + c] + (p[i] - mean) * rs * gamma[c];
        X1[(size_t)tok * kC + c] = (__bf16)v;
    }
}

// ---------------- LN(no-bias) + residual, natural order, fp32 out ----------------
__global__ __launch_bounds__(256) void k_ln_res2(const __bf16* __restrict__ F,
                                                 const __bf16* __restrict__ X1,
                                                 const float* __restrict__ gamma,
                                                 float* __restrict__ out)
{
    const int wave = threadIdx.x >> 6, lane = threadIdx.x & 63;
    const size_t tok = blockIdx.x * 4 + wave;

    float f[6]; float sum = 0.f, sq = 0.f;
    #pragma unroll
    for (int i = 0; i < 6; ++i) {
        f[i] = (float)F[tok * kC + lane + i * 64];
        sum += f[i]; sq += f[i] * f[i];
    }
    #pragma unroll
    for (int off = 32; off; off >>= 1) { sum += __shfl_xor(sum, off); sq += __shfl_xor(sq, off); }
    float mean = sum * (1.0f / kC);
    float var  = sq * (1.0f / kC) - mean * mean;
    float rs   = rsqrtf(var + 1e-5f);
    #pragma unroll
    for (int i = 0; i < 6; ++i) {
        int c = lane + i * 64;
        out[tok * kC + c] = (float)X1[tok * kC + c] + (f[i] - mean) * rs * gamma[c];
    }
}

extern "C" void kernel_launch(void* const* d_in, const int* in_sizes, int n_in,
                              void* d_out, int out_size, void* d_ws, size_t ws_size,
                              hipStream_t stream) {
    const float* x    = (const float*)d_in[0];
    const float* wqkv = (const float*)d_in[1];
    const float* wout = (const float*)d_in[2];
    const float* g_at = (const float*)d_in[3];
    const float* w1   = (const float*)d_in[4];
    const float* w2   = (const float*)d_in[5];
    const float* g_ff = (const float*)d_in[6];
    float* out = (float*)d_out;

    char* ws = (char*)d_ws;
    size_t off = 0;
    auto alloc = [&](size_t bytes) { size_t o = off; off += (bytes + 255) & ~(size_t)255; return o; };
    __bf16* WqkvT = (__bf16*)(ws + alloc((size_t)1152 * 384 * 2));
    __bf16* WoutT = (__bf16*)(ws + alloc((size_t)384 * 384 * 2));
    __bf16* W1T   = (__bf16*)(ws + alloc((size_t)1536 * 384 * 2));
    __bf16* W2T   = (__bf16*)(ws + alloc((size_t)384 * 1536 * 2));
    __bf16* R1    = (__bf16*)(ws + alloc((size_t)kNTOK * kDFF * 2));  // qkv (3*kNT) / FFN hidden
    __bf16* R2    = (__bf16*)(ws + alloc((size_t)kNT * 2));           // Aw -> AO -> X1
    __bf16* R3    = (__bf16*)(ws + alloc((size_t)kNT * 2));           // P -> F

    // weights -> bf16, transposed to N x K
    k_transpose_cast<<<dim3((384 * 1152 + 255) / 256), 256, 0, stream>>>(wqkv, WqkvT, 384, 1152);
    k_transpose_cast<<<dim3((384 * 384 + 255) / 256), 256, 0, stream>>>(wout, WoutT, 384, 384);
    k_transpose_cast<<<dim3((384 * 1536 + 255) / 256), 256, 0, stream>>>(w1, W1T, 384, 1536);
    k_transpose_cast<<<dim3((1536 * 384 + 255) / 256), 256, 0, stream>>>(w2, W2T, 1536, 384);

    // shift2d + window partition
    k_shift_window<<<dim3(12288), 256, 0, stream>>>(x, R2);

    // qkv projection (scatter epilogue into q/k/v): M=65536, N=1152, K=384
    k_gemm<0><<<dim3(512 * 9), 256, 0, stream>>>(R2, WqkvT, R1, 1152, 384, 9);

    // window attention (MFMA)
    k_attn<<<dim3(3072), 256, 0, stream>>>(R1, R2);

    // output projection: N=384, K=384
    k_gemm<1><<<dim3(512 * 3), 256, 0, stream>>>(R2, WoutT, R3, 384, 384, 3);

    // x1 = x + LN(attn)
    k_ln_res1<<<dim3(16384), 256, 0, stream>>>(R3, x, g_at, R2);

    // FFN up + gelu: N=1536, K=384
    k_gemm<2><<<dim3(512 * 12), 256, 0, stream>>>(R2, W1T, R1, 1536, 384, 12);

    // FFN down: N=384, K=1536
    k_gemm<1><<<dim3(512 * 3), 256, 0, stream>>>(R1, W2T, R3, 384, 1536, 3);

    // out = x1 + LN(f)
    k_ln_res2<<<dim3(16384), 256, 0, stream>>>(R3, R2, g_ff, out);
}

// Round 4
// 514.267 us; speedup vs baseline: 1.9008x; 1.0434x over previous
//
#include <hip/hip_runtime.h>
#include <hip/hip_bf16.h>
#include <math.h>

typedef __attribute__((ext_vector_type(8))) __bf16 bf16x8;
typedef __attribute__((ext_vector_type(4))) float f32x4;
typedef unsigned int uint32;

static constexpr int kC   = 384;
static constexpr int kNH  = 12;
static constexpr int kDH  = 32;
static constexpr int kT   = 64;      // tokens per window
static constexpr int kB   = 16;
static constexpr int kH   = 64;
static constexpr int kW   = 64;
static constexpr int kDFF = 1536;
static constexpr long kNTOK = 65536;             // B*H*W
static constexpr long kNT  = kNTOK * kC;         // elements of one (tokens x C) activation

__device__ __forceinline__ float bf_lo(uint32 u){ return __uint_as_float(u << 16); }
__device__ __forceinline__ float bf_hi(uint32 u){ return __uint_as_float(u & 0xffff0000u); }

// fast tanh-form gelu: 0.5x(1+tanh(0.79788456(x+0.044715x^3))) = x*e/(1+e),
// e = exp2(x*(A + B x^2)), A = 0.79788456*2.88539008, B = A*0.044715
__device__ __forceinline__ float gelu_fast(float x) {
    float x2 = x * x;
    float t  = fmaf(0.102944787f, x2, 2.302208165f);
    float m  = fminf(x * t, 80.0f);               // overflow guard
    float e  = __builtin_amdgcn_exp2f(m);
    float d  = 1.0f + e;
    return x * e * __builtin_amdgcn_rcpf(d);
}

// ---------------- weight transpose (K x N fp32 -> N x K bf16) ----------------
__global__ void k_transpose_cast(const float* __restrict__ src, __bf16* __restrict__ dst,
                                 int K, int N)
{
    int o = blockIdx.x * 256 + threadIdx.x;
    if (o >= K * N) return;
    int n = o / K, k = o - n * K;
    dst[o] = (__bf16)src[(size_t)k * N + n];
}

// ---------------- shift2d + window partition + bf16 cast ----------------
__global__ __launch_bounds__(256) void k_shift_window(const float* __restrict__ x,
                                                      __bf16* __restrict__ Aw)
{
    int tid = blockIdx.x * 256 + threadIdx.x;   // 0 .. 65536*48
    int m = tid / 48;
    int g = tid - m * 48;
    int c0 = g * 8;
    int wi = m >> 6, t = m & 63;
    int b = wi >> 6, nh = (wi >> 3) & 7, nw = wi & 7;
    int h = nh * 8 + (t >> 3);
    int w = nw * 8 + (t & 7);
    int q = c0 / 96;
    int sh = h, sw = w;
    bool ok;
    if      (q == 0) { sh = h - 1; ok = (h >= 1);  }
    else if (q == 1) { sh = h + 1; ok = (h <= 62); }
    else if (q == 2) { sw = w - 1; ok = (w >= 1);  }
    else             { sw = w + 1; ok = (w <= 62); }

    __bf16 r[8] __attribute__((aligned(16)));
    if (ok) {
        const float4* src = reinterpret_cast<const float4*>(
            x + (((size_t)b * kH + sh) * kW + sw) * kC + c0);
        float4 v0 = src[0], v1 = src[1];
        r[0] = (__bf16)v0.x; r[1] = (__bf16)v0.y; r[2] = (__bf16)v0.z; r[3] = (__bf16)v0.w;
        r[4] = (__bf16)v1.x; r[5] = (__bf16)v1.y; r[6] = (__bf16)v1.z; r[7] = (__bf16)v1.w;
    } else {
        #pragma unroll
        for (int i = 0; i < 8; ++i) r[i] = (__bf16)0.0f;
    }
    *reinterpret_cast<int4*>(Aw + (size_t)m * kC + c0) = *reinterpret_cast<int4*>(r);
}

// ---------------- generic bf16 MFMA GEMM: C = A(MxK) * B^T(NxK) ----------------
// Double-buffered LDS, both-sides bank swizzle, XCD-chunked 1-D grid (n-inner).
template<int EPI>
__global__ __launch_bounds__(256) void k_gemm(const __bf16* __restrict__ A,
                                              const __bf16* __restrict__ B,
                                              __bf16* __restrict__ Cout,
                                              int N, int K, int nt)
{
    __shared__ __align__(16) __bf16 As[2][128 * 32];
    __shared__ __align__(16) __bf16 Bs[2][128 * 32];
    const int tid  = threadIdx.x;
    const int wave = tid >> 6, lane = tid & 63;
    const int g = lane >> 4, qh = lane & 15;

    // XCD-aware bijective swizzle (nwg % 8 == 0 for all our launches), n-tile fastest
    const int nwg = gridDim.x;
    const int wg  = (blockIdx.x & 7) * (nwg >> 3) + (blockIdx.x >> 3);
    const int nb  = wg % nt, mb = wg / nt;
    const int m0 = mb * 128, n0 = nb * 128;
    const int wr = (wave >> 1) * 64, wc = (wave & 1) * 64;

    // read-side swizzled slot (bf16 units): slot = g ^ ((row>>1)&3)
    const int sw = ((g ^ ((lane >> 1) & 3)) << 3);

    auto STAGE = [&](int buf, int k0) {
        #pragma unroll
        for (int i = 0; i < 2; ++i) {
            int idx = tid + i * 256;          // 0..511
            int row = idx >> 2;
            int gseg = (idx & 3) ^ ((idx >> 3) & 3);   // pre-swizzled global source
            __builtin_amdgcn_global_load_lds(
                (const __attribute__((address_space(1))) void*)(A + (size_t)(m0 + row) * K + k0 + gseg * 8),
                (__attribute__((address_space(3))) void*)(&As[buf][idx * 8]), 16, 0, 0);
            __builtin_amdgcn_global_load_lds(
                (const __attribute__((address_space(1))) void*)(B + (size_t)(n0 + row) * K + k0 + gseg * 8),
                (__attribute__((address_space(3))) void*)(&Bs[buf][idx * 8]), 16, 0, 0);
        }
    };

    f32x4 acc[4][4] = {};
    const int nkt = K >> 5;

    STAGE(0, 0);
    for (int t = 0; t < nkt; ++t) {
        const int cur = t & 1;
        __syncthreads();                       // implicit vmcnt(0): drains tile-t loads (issued 1 iter ago)
        if (t + 1 < nkt) STAGE(cur ^ 1, (t + 1) << 5);

        bf16x8 af[4], bfr[4];
        #pragma unroll
        for (int mi = 0; mi < 4; ++mi) {
            int ra = wr + mi * 16 + qh;
            af[mi] = *reinterpret_cast<const bf16x8*>(&As[cur][ra * 32 + sw]);
        }
        #pragma unroll
        for (int ni = 0; ni < 4; ++ni) {
            int rb = wc + ni * 16 + qh;
            bfr[ni] = *reinterpret_cast<const bf16x8*>(&Bs[cur][rb * 32 + sw]);
        }
        __builtin_amdgcn_s_setprio(1);
        #pragma unroll
        for (int mi = 0; mi < 4; ++mi)
            #pragma unroll
            for (int ni = 0; ni < 4; ++ni)
                acc[mi][ni] = __builtin_amdgcn_mfma_f32_16x16x32_bf16(af[mi], bfr[ni], acc[mi][ni], 0, 0, 0);
        __builtin_amdgcn_s_setprio(0);
    }

    #pragma unroll
    for (int ni = 0; ni < 4; ++ni) {
        const int col = n0 + wc + ni * 16 + qh;
        // EPI 0 col-dependent pieces hoisted out of mi/r loops
        size_t cbase = 0;
        if constexpr (EPI == 0) {
            int s   = col / 384;
            int rem = col - s * 384;
            int hh  = rem >> 5, d = rem & 31;
            cbase = (size_t)s * kNT + ((size_t)hh * 64) * kDH + d;   // + win*kNH*64*kDH + trow*kDH
        }
        #pragma unroll
        for (int mi = 0; mi < 4; ++mi) {
            #pragma unroll
            for (int r = 0; r < 4; ++r) {
                int row = m0 + wr + mi * 16 + (g << 2) + r;
                float v = acc[mi][ni][r];
                if constexpr (EPI == 0) {
                    Cout[cbase + ((size_t)(row >> 6) * kNH * 64 + (row & 63)) * kDH] = (__bf16)v;
                } else if constexpr (EPI == 1) {
                    Cout[(size_t)row * N + col] = (__bf16)v;
                } else {
                    Cout[(size_t)row * N + col] = (__bf16)gelu_fast(v);
                }
            }
        }
    }
}

// ---------------- MFMA window attention: one wave per (window, head) ----------------
__global__ __launch_bounds__(256) void k_attn(const __bf16* __restrict__ qkv,
                                              __bf16* __restrict__ AO)
{
    __shared__ __bf16 Pl[4][kT * kT];   // 8 KB per wave, XOR-swizzled P tile
    const int wave = threadIdx.x >> 6, lane = threadIdx.x & 63;
    const int pair = blockIdx.x * 4 + wave;          // 0..12287
    const int wi = pair / kNH, hh = pair - wi * kNH;
    const int g = lane >> 4, qh = lane & 15;

    const __bf16* Qp = qkv + ((size_t)wi * kNH + hh) * (kT * kDH);
    const __bf16* Kp = Qp + kNT;
    const __bf16* Vp = Qp + 2 * kNT;
    char* Pb = (char*)&Pl[wave][0];

    bf16x8 qa[4], kb[4];
    #pragma unroll
    for (int mi = 0; mi < 4; ++mi)
        qa[mi] = *reinterpret_cast<const bf16x8*>(Qp + (mi * 16 + qh) * kDH + g * 8);
    #pragma unroll
    for (int ni = 0; ni < 4; ++ni)
        kb[ni] = *reinterpret_cast<const bf16x8*>(Kp + (ni * 16 + qh) * kDH + g * 8);

    f32x4 s[4][4] = {};
    #pragma unroll
    for (int mi = 0; mi < 4; ++mi)
        #pragma unroll
        for (int ni = 0; ni < 4; ++ni)
            s[mi][ni] = __builtin_amdgcn_mfma_f32_16x16x32_bf16(qa[mi], kb[ni], s[mi][ni], 0, 0, 0);

    const float scale = 0.17677669529663687f;  // 32^-0.5
    float rmax[4][4], rsum[4][4];
    #pragma unroll
    for (int mi = 0; mi < 4; ++mi)
        #pragma unroll
        for (int r = 0; r < 4; ++r) {
            float a = fmaxf(fmaxf(s[mi][0][r], s[mi][1][r]), fmaxf(s[mi][2][r], s[mi][3][r]));
            #pragma unroll
            for (int st = 1; st < 16; st <<= 1) a = fmaxf(a, __shfl_xor(a, st));
            rmax[mi][r] = a;
        }
    #pragma unroll
    for (int mi = 0; mi < 4; ++mi)
        #pragma unroll
        for (int r = 0; r < 4; ++r) {
            float acc = 0.f;
            #pragma unroll
            for (int ni = 0; ni < 4; ++ni) {
                float p = __expf((s[mi][ni][r] - rmax[mi][r]) * scale);
                s[mi][ni][r] = p;
                acc += p;
            }
            #pragma unroll
            for (int st = 1; st < 16; st <<= 1) acc += __shfl_xor(acc, st);
            rsum[mi][r] = 1.0f / acc;
        }

    #pragma unroll
    for (int mi = 0; mi < 4; ++mi)
        #pragma unroll
        for (int ni = 0; ni < 4; ++ni)
            #pragma unroll
            for (int r = 0; r < 4; ++r) {
                int row = mi * 16 + g * 4 + r;
                int col = ni * 16 + qh;
                uint32 byte = (uint32)((row << 7) | (col << 1)) ^ (uint32)((row & 7) << 4);
                *reinterpret_cast<__bf16*>(Pb + byte) = (__bf16)s[mi][ni][r];
            }

    f32x4 o[4][2] = {};
    #pragma unroll
    for (int kk = 0; kk < 2; ++kk) {
        bf16x8 pa[4], vb[2];
        #pragma unroll
        for (int mi = 0; mi < 4; ++mi) {
            int row = mi * 16 + qh;
            uint32 byte = (uint32)((row << 7) | (kk << 6) | (g << 4)) ^ (uint32)((row & 7) << 4);
            pa[mi] = *reinterpret_cast<const bf16x8*>(Pb + byte);
        }
        #pragma unroll
        for (int n2 = 0; n2 < 2; ++n2) {
            __bf16 tmp[8];
            #pragma unroll
            for (int j = 0; j < 8; ++j)
                tmp[j] = Vp[(kk * 32 + g * 8 + j) * kDH + n2 * 16 + qh];
            vb[n2] = *reinterpret_cast<const bf16x8*>(tmp);
        }
        #pragma unroll
        for (int mi = 0; mi < 4; ++mi)
            #pragma unroll
            for (int n2 = 0; n2 < 2; ++n2)
                o[mi][n2] = __builtin_amdgcn_mfma_f32_16x16x32_bf16(pa[mi], vb[n2], o[mi][n2], 0, 0, 0);
    }

    #pragma unroll
    for (int mi = 0; mi < 4; ++mi)
        #pragma unroll
        for (int n2 = 0; n2 < 2; ++n2)
            #pragma unroll
            for (int r = 0; r < 4; ++r) {
                int row = mi * 16 + g * 4 + r;
                AO[((size_t)wi * 64 + row) * kC + hh * kDH + n2 * 16 + qh] =
                    (__bf16)(o[mi][n2][r] * rsum[mi][r]);
            }
}

// ---------------- LN(no-bias) + residual, window-order input ----------------
__global__ __launch_bounds__(256) void k_ln_res1(const __bf16* __restrict__ P,
                                                 const float* __restrict__ x,
                                                 const float* __restrict__ gamma,
                                                 __bf16* __restrict__ X1)
{
    const int wave = threadIdx.x >> 6, lane = threadIdx.x & 63;
    const int tok = blockIdx.x * 4 + wave;     // natural: b*4096 + h*64 + w
    const int b = tok >> 12, hw = tok & 4095, h = hw >> 6, w = hw & 63;
    const int m = (((b << 6) | ((h >> 3) << 3) | (w >> 3)) << 6) | (((h & 7) << 3) | (w & 7));

    float p[6]; float sum = 0.f, sq = 0.f;
    #pragma unroll
    for (int i = 0; i < 6; ++i) {
        p[i] = (float)P[(size_t)m * kC + lane + i * 64];
        sum += p[i]; sq += p[i] * p[i];
    }
    #pragma unroll
    for (int off = 32; off; off >>= 1) { sum += __shfl_xor(sum, off); sq += __shfl_xor(sq, off); }
    float mean = sum * (1.0f / kC);
    float var  = sq * (1.0f / kC) - mean * mean;
    float rs   = rsqrtf(var + 1e-5f);
    #pragma unroll
    for (int i = 0; i < 6; ++i) {
        int c = lane + i * 64;
        float v = x[(size_t)tok * kC + c] + (p[i] - mean) * rs * gamma[c];
        X1[(size_t)tok * kC + c] = (__bf16)v;
    }
}

// ---------------- LN(no-bias) + residual, natural order, fp32 out ----------------
__global__ __launch_bounds__(256) void k_ln_res2(const __bf16* __restrict__ F,
                                                 const __bf16* __restrict__ X1,
                                                 const float* __restrict__ gamma,
                                                 float* __restrict__ out)
{
    const int wave = threadIdx.x >> 6, lane = threadIdx.x & 63;
    const size_t tok = blockIdx.x * 4 + wave;

    float f[6]; float sum = 0.f, sq = 0.f;
    #pragma unroll
    for (int i = 0; i < 6; ++i) {
        f[i] = (float)F[tok * kC + lane + i * 64];
        sum += f[i]; sq += f[i] * f[i];
    }
    #pragma unroll
    for (int off = 32; off; off >>= 1) { sum += __shfl_xor(sum, off); sq += __shfl_xor(sq, off); }
    float mean = sum * (1.0f / kC);
    float var  = sq * (1.0f / kC) - mean * mean;
    float rs   = rsqrtf(var + 1e-5f);
    #pragma unroll
    for (int i = 0; i < 6; ++i) {
        int c = lane + i * 64;
        out[tok * kC + c] = (float)X1[tok * kC + c] + (f[i] - mean) * rs * gamma[c];
    }
}

extern "C" void kernel_launch(void* const* d_in, const int* in_sizes, int n_in,
                              void* d_out, int out_size, void* d_ws, size_t ws_size,
                              hipStream_t stream) {
    const float* x    = (const float*)d_in[0];
    const float* wqkv = (const float*)d_in[1];
    const float* wout = (const float*)d_in[2];
    const float* g_at = (const float*)d_in[3];
    const float* w1   = (const float*)d_in[4];
    const float* w2   = (const float*)d_in[5];
    const float* g_ff = (const float*)d_in[6];
    float* out = (float*)d_out;

    char* ws = (char*)d_ws;
    size_t off = 0;
    auto alloc = [&](size_t bytes) { size_t o = off; off += (bytes + 255) & ~(size_t)255; return o; };
    __bf16* WqkvT = (__bf16*)(ws + alloc((size_t)1152 * 384 * 2));
    __bf16* WoutT = (__bf16*)(ws + alloc((size_t)384 * 384 * 2));
    __bf16* W1T   = (__bf16*)(ws + alloc((size_t)1536 * 384 * 2));
    __bf16* W2T   = (__bf16*)(ws + alloc((size_t)384 * 1536 * 2));
    __bf16* R1    = (__bf16*)(ws + alloc((size_t)kNTOK * kDFF * 2));  // qkv (3*kNT) / FFN hidden
    __bf16* R2    = (__bf16*)(ws + alloc((size_t)kNT * 2));           // Aw -> AO -> X1
    __bf16* R3    = (__bf16*)(ws + alloc((size_t)kNT * 2));           // P -> F

    // weights -> bf16, transposed to N x K
    k_transpose_cast<<<dim3((384 * 1152 + 255) / 256), 256, 0, stream>>>(wqkv, WqkvT, 384, 1152);
    k_transpose_cast<<<dim3((384 * 384 + 255) / 256), 256, 0, stream>>>(wout, WoutT, 384, 384);
    k_transpose_cast<<<dim3((384 * 1536 + 255) / 256), 256, 0, stream>>>(w1, W1T, 384, 1536);
    k_transpose_cast<<<dim3((1536 * 384 + 255) / 256), 256, 0, stream>>>(w2, W2T, 1536, 384);

    // shift2d + window partition
    k_shift_window<<<dim3(12288), 256, 0, stream>>>(x, R2);

    // qkv projection (scatter epilogue into q/k/v): M=65536, N=1152, K=384
    k_gemm<0><<<dim3(512 * 9), 256, 0, stream>>>(R2, WqkvT, R1, 1152, 384, 9);

    // window attention (MFMA)
    k_attn<<<dim3(3072), 256, 0, stream>>>(R1, R2);

    // output projection: N=384, K=384
    k_gemm<1><<<dim3(512 * 3), 256, 0, stream>>>(R2, WoutT, R3, 384, 384, 3);

    // x1 = x + LN(attn)
    k_ln_res1<<<dim3(16384), 256, 0, stream>>>(R3, x, g_at, R2);

    // FFN up + gelu: N=1536, K=384
    k_gemm<2><<<dim3(512 * 12), 256, 0, stream>>>(R2, W1T, R1, 1536, 384, 12);

    // FFN down: N=384, K=1536
    k_gemm<1><<<dim3(512 * 3), 256, 0, stream>>>(R1, W2T, R3, 384, 1536, 3);

    // out = x1 + LN(f)
    k_ln_res2<<<dim3(16384), 256, 0, stream>>>(R3, R2, g_ff, out);
}